// Round 2
// baseline (331.597 us; speedup 1.0000x reference)
//
#include <hip/hip_runtime.h>

// Self-attention block (non-local): B=8, C=256, H=W=64 -> N=4096, dk=64.
// out = x + gamma * softmax((Wq x)^T (Wk x) / 8) applied to (Wv x).
// Pipeline: prep (weights->bf16, fold log2e/8 into Wq) -> proj (MFMA GEMM,
// in-LDS transpose of x) -> flash (shared-P attention: per 256-kv block each
// wave computes S for a 64-kv slice, packs P into swizzled LDS (dbuf, one
// barrier/iter), then all waves do PV for their 64-channel slice; max-free
// softmax, fused residual epilogue).  Batch<->XCD chunked block swizzle.

typedef __attribute__((ext_vector_type(8)))  short short8;
typedef __attribute__((ext_vector_type(4)))  short short4v;
typedef __attribute__((ext_vector_type(16))) float f32x16;
typedef __attribute__((ext_vector_type(4)))  float f32x4;

#define B_   8
#define C_   256
#define N_   4096
#define DK_  64
// log2(e) / sqrt(dk) = 1.4426950408889634 / 8
#define QSCL 0.18033688011112043f

#if defined(__has_builtin)
#if __has_builtin(__builtin_amdgcn_exp2f)
#define EXP2F(x) __builtin_amdgcn_exp2f(x)
#else
#define EXP2F(x) exp2f(x)
#endif
#else
#define EXP2F(x) exp2f(x)
#endif

// float -> bf16 bits, round-to-nearest-even (inputs are finite; no NaN path)
__device__ __forceinline__ unsigned short bfb(float f) {
  unsigned u = __builtin_bit_cast(unsigned, f);
  unsigned r = (u + 0x7fffu + ((u >> 16) & 1u)) >> 16;
  return (unsigned short)r;
}

__device__ __forceinline__ unsigned pk2(float a, float b) {
  return ((unsigned)bfb(b) << 16) | (unsigned)bfb(a);
}

// ---------------------------------------------------------------------------
// Kernel 1: weight prep.  W'[384][256] bf16 = [Wq*QSCL ; Wk ; Wv], bias'[384].
// ---------------------------------------------------------------------------
__global__ void prep_kernel(const float* __restrict__ Wq, const float* __restrict__ bq,
                            const float* __restrict__ Wk, const float* __restrict__ bk,
                            const float* __restrict__ Wv, const float* __restrict__ bv,
                            unsigned short* __restrict__ Wc, float* __restrict__ biasc) {
  int idx = blockIdx.x * 256 + threadIdx.x;
  if (idx < 384 * 256) {
    int ch = idx >> 8, c = idx & 255;
    float v;
    if (ch < 64)       v = Wq[ch * 256 + c] * QSCL;
    else if (ch < 128) v = Wk[(ch - 64) * 256 + c];
    else               v = Wv[(ch - 128) * 256 + c];
    Wc[idx] = bfb(v);
  }
  if (idx < 384) {
    float bb;
    if (idx < 64)       bb = bq[idx] * QSCL;
    else if (idx < 128) bb = bk[idx - 64];
    else                bb = bv[idx - 128];
    biasc[idx] = bb;
  }
}

// ---------------------------------------------------------------------------
// Kernel 2: projections.  Per (batch, 64-row n-block): stage x[256c][64n]
// transposed into LDS as bf16 (XOR-swizzled), then OUT[n][ch] = Xt * W'^T via
// 32x32x16 bf16 MFMA.  Outputs: Qt,Kt [B][N][64] (n-major), V [B][C][N].
// ---------------------------------------------------------------------------
__global__ __launch_bounds__(256, 2) void proj_kernel(
    const float* __restrict__ x, const unsigned short* __restrict__ Wc,
    const float* __restrict__ biasc, unsigned short* __restrict__ Qt,
    unsigned short* __restrict__ Kt, unsigned short* __restrict__ V) {
  __shared__ unsigned short XT[64 * 256];  // [n][c] bf16, swizzled, 32 KiB
  const int tid = threadIdx.x;
  const int b = blockIdx.y;
  const int n0 = blockIdx.x * 64;

  // stage: x[b][c][n0+0..63] fp32 -> XT[n][c] bf16 (transpose), swizzle:
  // ushort idx = n*256 + (((c>>3) ^ (n&15))<<3) + (c&7)
  {
    const f32x4* x4 = (const f32x4*)(x + ((size_t)b * C_) * N_ + n0);
    int c = tid >> 4;                  // 0..15 (+16 per pass)
    const int nl = (tid & 15) << 2;    // 0,4,...,60
#pragma unroll
    for (int p = 0; p < 16; ++p, c += 16) {
      f32x4 v = x4[(size_t)c * (N_ / 4) + (nl >> 2)];
#pragma unroll
      for (int i = 0; i < 4; ++i) {
        int n = nl + i;
        XT[n * 256 + ((((c >> 3) ^ (n & 15)) << 3) | (c & 7))] = bfb(v[i]);
      }
    }
  }
  __syncthreads();

  const int lane = tid & 63, li = lane & 31, hi = lane >> 5;
  const int w = tid >> 6;
  const int ch0 = 96 * w;  // this wave's 96 output channels (3 x 32)

  f32x16 acc[2][3];
#pragma unroll
  for (int mt = 0; mt < 2; ++mt)
#pragma unroll
    for (int j = 0; j < 3; ++j)
#pragma unroll
      for (int r = 0; r < 16; ++r) acc[mt][j][r] = 0.f;

  const short8* Wc8 = (const short8*)Wc;
#pragma unroll
  for (int ks = 0; ks < 16; ++ks) {
    // A-frags: lane holds Xt[n=32*mt+li][c=16*ks+8*hi .. +8]
    int chunk = 2 * ks + hi;
    short8 a0 = *(const short8*)&XT[(li) * 256 + ((chunk ^ (li & 15)) << 3)];
    short8 a1 = *(const short8*)&XT[(32 + li) * 256 + ((chunk ^ (li & 15)) << 3)];
#pragma unroll
    for (int j = 0; j < 3; ++j) {
      short8 bf = Wc8[(size_t)(ch0 + 32 * j + li) * 32 + chunk];
      acc[0][j] = __builtin_amdgcn_mfma_f32_32x32x16_bf16(a0, bf, acc[0][j], 0, 0, 0);
      acc[1][j] = __builtin_amdgcn_mfma_f32_32x32x16_bf16(a1, bf, acc[1][j], 0, 0, 0);
    }
  }

  // epilogue: D[row=n][col=ch], row = (r&3)+8*(r>>2)+4*hi + 32*mt, col = li
#pragma unroll
  for (int j = 0; j < 3; ++j) {
    const int chb = ch0 + 32 * j;  // wave-uniform 32-block, never straddles Q/K/V
    const int ch = chb + li;
    const float bias = biasc[ch];
#pragma unroll
    for (int mt = 0; mt < 2; ++mt) {
      if (chb < 64) {
#pragma unroll
        for (int r = 0; r < 16; ++r) {
          int n = n0 + 32 * mt + (r & 3) + 8 * (r >> 2) + 4 * hi;
          Qt[((size_t)(b * N_ + n) << 6) + ch] = bfb(acc[mt][j][r] + bias);
        }
      } else if (chb < 128) {
#pragma unroll
        for (int r = 0; r < 16; ++r) {
          int n = n0 + 32 * mt + (r & 3) + 8 * (r >> 2) + 4 * hi;
          Kt[((size_t)(b * N_ + n) << 6) + (ch - 64)] = bfb(acc[mt][j][r] + bias);
        }
      } else {
        const int cv = ch - 128;
#pragma unroll
        for (int q = 0; q < 4; ++q) {  // 4 consecutive n per 8B store
          short4v pk;
#pragma unroll
          for (int i = 0; i < 4; ++i) pk[i] = (short)bfb(acc[mt][j][4 * q + i] + bias);
          int n = n0 + 32 * mt + 8 * q + 4 * hi;
          *(short4v*)&V[(size_t)(b * C_ + cv) * N_ + n] = pk;
        }
      }
    }
  }
}

// ---------------------------------------------------------------------------
// Kernel 3: attention, shared-P.  Grid 1024 x 256 threads (4 waves).
// Block id: b = id & 7 (batch <-> XCD), m0 = (id >> 3) * 32.
// Per kv-block of 256: wave w computes S for kv-slice [64w,64w+64) x 32 m,
// writes P (bf16) into swizzled LDS (double-buffered, 1 barrier/iter); then
// each wave does PV for channel slice [64w,64w+64) reading all 256 P-cols.
// LDS addr of P[m][n] (bytes): m*512 + 16*((n>>3) ^ m) + (2n & 15).
// ---------------------------------------------------------------------------
__global__ __launch_bounds__(256, 4) void flash_kernel(
    const unsigned short* __restrict__ Qt, const unsigned short* __restrict__ Kt,
    const unsigned short* __restrict__ V, const float* __restrict__ x,
    const float* __restrict__ gamma, float* __restrict__ out) {
  __shared__ union {
    unsigned short P[2][32 * 256];   // 2 x 16 KiB, swizzled
    float TB[4][32 * 33];            // epilogue transpose (per-wave 4224 B)
  } sm;
  __shared__ float den_lds[4][32];

  const int tid = threadIdx.x;
  const int lane = tid & 63, li = lane & 31, hi = lane >> 5;
  const int w = tid >> 6;
  const int id = blockIdx.x;
  const int b = id & 7;                // batch == XCD (round-robin dispatch)
  const int m0 = (id >> 3) << 5;       // 32-row m-block

  const short8* Qt8 = (const short8*)Qt;
  const short8* Kt8 = (const short8*)Kt;
  const short8* V8 = (const short8*)V;

  // Q B-frags: lane holds Qt[m0+li][16*ks+8*hi .. +8]
  short8 qb[4];
#pragma unroll
  for (int ks = 0; ks < 4; ++ks)
    qb[ks] = Qt8[((size_t)b * N_ + m0 + li) * 8 + 2 * ks + hi];

  f32x16 acc[2];
#pragma unroll
  for (int ct = 0; ct < 2; ++ct)
#pragma unroll
    for (int r = 0; r < 16; ++r) acc[ct][r] = 0.f;
  float den = 0.f;

  const int rowbase = li * 512;        // byte offset of LDS row m=li
  const int swz = li << 4;             // slot-level XOR swizzle
  const size_t vr0 = ((size_t)b * C_ + 64 * w + li) * (N_ / 8);
  const size_t vr1 = vr0 + (size_t)32 * (N_ / 8);
  const size_t krow = (size_t)b * N_ + 64 * w + li;

  for (int t = 0; t < 16; ++t) {
    const int kv0 = t << 8;
    char* Pb = (char*)sm.P[t & 1];

    // ---- phase 1: S for kv-slice [kv0+64w, +64), all 32 m-rows ----
    short8 kf[2][4];
#pragma unroll
    for (int nt = 0; nt < 2; ++nt)
#pragma unroll
      for (int ks = 0; ks < 4; ++ks)
        kf[nt][ks] = Kt8[(krow + kv0 + 32 * nt) * 8 + 2 * ks + hi];

#pragma unroll
    for (int nt = 0; nt < 2; ++nt) {
      f32x16 st;
#pragma unroll
      for (int r = 0; r < 16; ++r) st[r] = 0.f;
#pragma unroll
      for (int ks = 0; ks < 4; ++ks)
        st = __builtin_amdgcn_mfma_f32_32x32x16_bf16(kf[nt][ks], qb[ks], st, 0, 0, 0);
      // St[n][m]: lane holds m = li, n_local = (r&3)+8*(r>>2)+4*hi
      float e[16];
      float ds = 0.f;
#pragma unroll
      for (int r = 0; r < 16; ++r) {
        e[r] = EXP2F(st[r]);
        ds += e[r];
      }
      den += ds;
      // e[4u..4u+3] are n = 64w+32nt+8u+4hi+{0..3}: one 8-byte LDS write each
#pragma unroll
      for (int u = 0; u < 4; ++u) {
        unsigned lo = pk2(e[4 * u], e[4 * u + 1]);
        unsigned hh = pk2(e[4 * u + 2], e[4 * u + 3]);
        unsigned long long vv = (unsigned long long)lo | ((unsigned long long)hh << 32);
        int colbyte = 128 * w + 64 * nt + 16 * u + 8 * hi;
        *(unsigned long long*)(Pb + rowbase + (colbyte ^ swz)) = vv;
      }
    }
    __syncthreads();  // P[t&1] complete; dbuf protects write-after-read

    // ---- phase 2: PV for channel slice, all 256 kv of this block ----
#pragma unroll
    for (int ks = 0; ks < 16; ++ks) {
      const short8 pf = *(const short8*)(Pb + rowbase + ((32 * ks + 16 * hi) ^ swz));
      short8 v0 = V8[vr0 + (kv0 >> 3) + 2 * ks + hi];
      short8 v1 = V8[vr1 + (kv0 >> 3) + 2 * ks + hi];
      acc[0] = __builtin_amdgcn_mfma_f32_32x32x16_bf16(pf, v0, acc[0], 0, 0, 0);
      acc[1] = __builtin_amdgcn_mfma_f32_32x32x16_bf16(pf, v1, acc[1], 0, 0, 0);
    }
  }

  // ---- den reduction across waves ----
  float dh = den + __shfl_xor(den, 32);     // full kv-slice of wave w, m=li
  if (hi == 0) den_lds[w][li] = dh;
  __syncthreads();                          // also: all P reads done (TB aliases P)
  float dtot = den_lds[0][li] + den_lds[1][li] + den_lds[2][li] + den_lds[3][li];
  const float ig = gamma[0] / dtot;         // per m=li: gamma/den

  float idn[16];
#pragma unroll
  for (int r = 0; r < 16; ++r)
    idn[r] = __shfl(ig, (r & 3) + 8 * (r >> 2) + 4 * hi);

  // ---- epilogue: transpose 32x32 per ct via LDS, out = x + (gamma/den)*o ----
#pragma unroll
  for (int ct = 0; ct < 2; ++ct) {
#pragma unroll
    for (int r = 0; r < 16; ++r) {
      int mrel = (r & 3) + 8 * (r >> 2) + 4 * hi;
      sm.TB[w][mrel * 33 + li] = acc[ct][r] * idn[r];
    }
    __builtin_amdgcn_s_waitcnt(0);  // lgkmcnt(0): LDS writes visible in-wave
#pragma unroll
    for (int p = 0; p < 4; ++p) {
      int cl = (lane >> 3) + 8 * p;   // c within tile 0..31
      int mc = (lane & 7) * 4;        // m chunk 0..28
      f32x4 o;
#pragma unroll
      for (int i = 0; i < 4; ++i) o[i] = sm.TB[w][(mc + i) * 33 + cl];
      size_t off = ((size_t)b * C_ + 64 * w + 32 * ct + cl) * N_ + m0 + mc;
      f32x4 xv = *(const f32x4*)(x + off);
#pragma unroll
      for (int i = 0; i < 4; ++i) o[i] = xv[i] + o[i];
      *(f32x4*)(out + off) = o;
    }
    __builtin_amdgcn_s_waitcnt(0);  // drain reads before next tile overwrites
  }
}

// ---------------------------------------------------------------------------
extern "C" void kernel_launch(void* const* d_in, const int* in_sizes, int n_in,
                              void* d_out, int out_size, void* d_ws, size_t ws_size,
                              hipStream_t stream) {
  const float* x = (const float*)d_in[0];
  const float* Wq = (const float*)d_in[1];
  const float* bq = (const float*)d_in[2];
  const float* Wk = (const float*)d_in[3];
  const float* bk = (const float*)d_in[4];
  const float* Wv = (const float*)d_in[5];
  const float* bv = (const float*)d_in[6];
  const float* gamma = (const float*)d_in[7];
  float* out = (float*)d_out;

  char* ws = (char*)d_ws;
  unsigned short* Wc = (unsigned short*)(ws);                    // 196608 B
  float* biasc = (float*)(ws + 196608);                          // 1536 B
  unsigned short* Qt = (unsigned short*)(ws + 198144);           // 4 MiB
  unsigned short* Kt = (unsigned short*)(ws + 198144 + 4194304); // 4 MiB
  unsigned short* Vv = (unsigned short*)(ws + 198144 + 8388608); // 16 MiB
  // total ws use: ~25.4 MB

  prep_kernel<<<384, 256, 0, stream>>>(Wq, bq, Wk, bk, Wv, bv, Wc, biasc);
  proj_kernel<<<dim3(64, 8), 256, 0, stream>>>(x, Wc, biasc, Qt, Kt, Vv);
  flash_kernel<<<1024, 256, 0, stream>>>(Qt, Kt, Vv, x, gamma, out);
}

// Round 3
// 220.333 us; speedup vs baseline: 1.5050x; 1.5050x over previous
//
#include <hip/hip_runtime.h>

// Self-attention block (non-local): B=8, C=256, H=W=64 -> N=4096, dk=64.
// out = x + gamma * softmax((Wq x)^T (Wk x) / 8) applied to (Wv x).
// Pipeline: prep (weights->bf16, fold log2e/8 into Wq) -> proj (MFMA GEMM,
// in-LDS transpose of x) -> flash (shared-P attention, m-block 64: per 256-kv
// block each wave computes S for a 64-kv slice, packs P into swizzled LDS
// (dbuf, 1 barrier/iter), then all waves do PV for their 64-channel slice.
// Max-free softmax (logits O(1) by construction), fused residual epilogue.
// R3: launch_bounds(256,2) for register headroom + manual V prefetch (ct0
// whole-block during phase 1; ct1 4-deep ring) to un-expose L2 latency.

typedef __attribute__((ext_vector_type(8)))  short short8;
typedef __attribute__((ext_vector_type(4)))  short short4v;
typedef __attribute__((ext_vector_type(16))) float f32x16;
typedef __attribute__((ext_vector_type(4)))  float f32x4;

#define B_   8
#define C_   256
#define N_   4096
#define DK_  64
// log2(e) / sqrt(dk) = 1.4426950408889634 / 8
#define QSCL 0.18033688011112043f

#if defined(__has_builtin)
#if __has_builtin(__builtin_amdgcn_exp2f)
#define EXP2F(x) __builtin_amdgcn_exp2f(x)
#else
#define EXP2F(x) exp2f(x)
#endif
#else
#define EXP2F(x) exp2f(x)
#endif

// float -> bf16 bits, round-to-nearest-even (inputs are finite; no NaN path)
__device__ __forceinline__ unsigned short bfb(float f) {
  unsigned u = __builtin_bit_cast(unsigned, f);
  unsigned r = (u + 0x7fffu + ((u >> 16) & 1u)) >> 16;
  return (unsigned short)r;
}

// packed f32x2 -> bf16x2 (low = a, high = b), RNE
__device__ __forceinline__ unsigned cvtpk(float a, float b) {
  unsigned r;
  asm("v_cvt_pk_bf16_f32 %0, %1, %2" : "=v"(r) : "v"(a), "v"(b));
  return r;
}

// ---------------------------------------------------------------------------
// Kernel 1: weight prep.  W'[384][256] bf16 = [Wq*QSCL ; Wk ; Wv], bias'[384].
// ---------------------------------------------------------------------------
__global__ void prep_kernel(const float* __restrict__ Wq, const float* __restrict__ bq,
                            const float* __restrict__ Wk, const float* __restrict__ bk,
                            const float* __restrict__ Wv, const float* __restrict__ bv,
                            unsigned short* __restrict__ Wc, float* __restrict__ biasc) {
  int idx = blockIdx.x * 256 + threadIdx.x;
  if (idx < 384 * 256) {
    int ch = idx >> 8, c = idx & 255;
    float v;
    if (ch < 64)       v = Wq[ch * 256 + c] * QSCL;
    else if (ch < 128) v = Wk[(ch - 64) * 256 + c];
    else               v = Wv[(ch - 128) * 256 + c];
    Wc[idx] = bfb(v);
  }
  if (idx < 384) {
    float bb;
    if (idx < 64)       bb = bq[idx] * QSCL;
    else if (idx < 128) bb = bk[idx - 64];
    else                bb = bv[idx - 128];
    biasc[idx] = bb;
  }
}

// ---------------------------------------------------------------------------
// Kernel 2: projections.  Per (batch, 64-row n-block): stage x[256c][64n]
// transposed into LDS as bf16 (XOR-swizzled), then OUT[n][ch] = Xt * W'^T via
// 32x32x16 bf16 MFMA.  Outputs: Qt,Kt [B][N][64] (n-major), V [B][C][N].
// ---------------------------------------------------------------------------
__global__ __launch_bounds__(256, 2) void proj_kernel(
    const float* __restrict__ x, const unsigned short* __restrict__ Wc,
    const float* __restrict__ biasc, unsigned short* __restrict__ Qt,
    unsigned short* __restrict__ Kt, unsigned short* __restrict__ V) {
  __shared__ unsigned short XT[64 * 256];  // [n][c] bf16, swizzled, 32 KiB
  const int tid = threadIdx.x;
  const int b = blockIdx.y;
  const int n0 = blockIdx.x * 64;

  // stage: x[b][c][n0+0..63] fp32 -> XT[n][c] bf16 (transpose), swizzle:
  // ushort idx = n*256 + (((c>>3) ^ (n&15))<<3) + (c&7)
  {
    const f32x4* x4 = (const f32x4*)(x + ((size_t)b * C_) * N_ + n0);
    int c = tid >> 4;                  // 0..15 (+16 per pass)
    const int nl = (tid & 15) << 2;    // 0,4,...,60
#pragma unroll
    for (int p = 0; p < 16; ++p, c += 16) {
      f32x4 v = x4[(size_t)c * (N_ / 4) + (nl >> 2)];
#pragma unroll
      for (int i = 0; i < 4; ++i) {
        int n = nl + i;
        XT[n * 256 + ((((c >> 3) ^ (n & 15)) << 3) | (c & 7))] = bfb(v[i]);
      }
    }
  }
  __syncthreads();

  const int lane = tid & 63, li = lane & 31, hi = lane >> 5;
  const int w = tid >> 6;
  const int ch0 = 96 * w;  // this wave's 96 output channels (3 x 32)

  f32x16 acc[2][3];
#pragma unroll
  for (int mt = 0; mt < 2; ++mt)
#pragma unroll
    for (int j = 0; j < 3; ++j)
#pragma unroll
      for (int r = 0; r < 16; ++r) acc[mt][j][r] = 0.f;

  const short8* Wc8 = (const short8*)Wc;
#pragma unroll
  for (int ks = 0; ks < 16; ++ks) {
    // A-frags: lane holds Xt[n=32*mt+li][c=16*ks+8*hi .. +8]
    int chunk = 2 * ks + hi;
    short8 a0 = *(const short8*)&XT[(li) * 256 + ((chunk ^ (li & 15)) << 3)];
    short8 a1 = *(const short8*)&XT[(32 + li) * 256 + ((chunk ^ (li & 15)) << 3)];
#pragma unroll
    for (int j = 0; j < 3; ++j) {
      short8 bf = Wc8[(size_t)(ch0 + 32 * j + li) * 32 + chunk];
      acc[0][j] = __builtin_amdgcn_mfma_f32_32x32x16_bf16(a0, bf, acc[0][j], 0, 0, 0);
      acc[1][j] = __builtin_amdgcn_mfma_f32_32x32x16_bf16(a1, bf, acc[1][j], 0, 0, 0);
    }
  }

  // epilogue: D[row=n][col=ch], row = (r&3)+8*(r>>2)+4*hi + 32*mt, col = li
#pragma unroll
  for (int j = 0; j < 3; ++j) {
    const int chb = ch0 + 32 * j;  // wave-uniform 32-block, never straddles Q/K/V
    const int ch = chb + li;
    const float bias = biasc[ch];
#pragma unroll
    for (int mt = 0; mt < 2; ++mt) {
      if (chb < 64) {
#pragma unroll
        for (int r = 0; r < 16; ++r) {
          int n = n0 + 32 * mt + (r & 3) + 8 * (r >> 2) + 4 * hi;
          Qt[((size_t)(b * N_ + n) << 6) + ch] = bfb(acc[mt][j][r] + bias);
        }
      } else if (chb < 128) {
#pragma unroll
        for (int r = 0; r < 16; ++r) {
          int n = n0 + 32 * mt + (r & 3) + 8 * (r >> 2) + 4 * hi;
          Kt[((size_t)(b * N_ + n) << 6) + (ch - 64)] = bfb(acc[mt][j][r] + bias);
        }
      } else {
        const int cv = ch - 128;
#pragma unroll
        for (int q = 0; q < 4; ++q) {  // 4 consecutive n per 8B store
          short4v pk;
#pragma unroll
          for (int i = 0; i < 4; ++i) pk[i] = (short)bfb(acc[mt][j][4 * q + i] + bias);
          int n = n0 + 32 * mt + 8 * q + 4 * hi;
          *(short4v*)&V[(size_t)(b * C_ + cv) * N_ + n] = pk;
        }
      }
    }
  }
}

// ---------------------------------------------------------------------------
// Kernel 3: attention, shared-P, m-block 64.  Grid 512 x 256 threads (4 waves).
// Block id: b = id & 7 (batch <-> XCD), m0 = (id >> 3) * 64.
// Per kv-block of 256: wave w computes S for kv-slice [64w,64w+64) x 64 m
// (2 m-tiles), writes P (bf16) into swizzled LDS (double-buffered, 1
// barrier/iter); then each wave does PV for channel slice [64w,64w+64)
// reading all 256 P-cols.  LDS addr of P[m][n] (bytes):
//   m*512 + ((2n & ~15) ^ ((m&31)<<4)) + (2n & 15).
// ---------------------------------------------------------------------------
__global__ __launch_bounds__(256, 2) void flash_kernel(
    const unsigned short* __restrict__ Qt, const unsigned short* __restrict__ Kt,
    const unsigned short* __restrict__ V, const float* __restrict__ x,
    const float* __restrict__ gamma, float* __restrict__ out) {
  __shared__ union {
    unsigned short P[2][64 * 256];   // 2 x 32 KiB, swizzled
    float TB[4][32 * 33];            // epilogue transpose (per-wave 4224 B)
  } sm;
  __shared__ float den_lds[4][2][32];

  const int tid = threadIdx.x;
  const int lane = tid & 63, li = lane & 31, hi = lane >> 5;
  const int w = tid >> 6;
  const int id = blockIdx.x;
  const int b = id & 7;                // batch == XCD (round-robin dispatch)
  const int m0 = (id >> 3) << 6;       // 64-row m-block

  const short8* Qt8 = (const short8*)Qt;
  const short8* Kt8 = (const short8*)Kt;
  const short8* V8 = (const short8*)V;

  // Q B-frags: lane holds Qt[m0+32*mt+li][16*ks+8*hi .. +8]
  short8 qb[2][4];
#pragma unroll
  for (int mt = 0; mt < 2; ++mt)
#pragma unroll
    for (int ks = 0; ks < 4; ++ks)
      qb[mt][ks] = Qt8[((size_t)b * N_ + m0 + 32 * mt + li) * 8 + 2 * ks + hi];

  f32x16 acc[2][2];  // [mt][ct]
#pragma unroll
  for (int mt = 0; mt < 2; ++mt)
#pragma unroll
    for (int ct = 0; ct < 2; ++ct)
#pragma unroll
      for (int r = 0; r < 16; ++r) acc[mt][ct][r] = 0.f;
  float den[2] = {0.f, 0.f};

  const int swz = li << 4;             // slot-level XOR swizzle (row & 31)
  const size_t vr0 = ((size_t)b * C_ + 64 * w + li) * (N_ / 8);
  const size_t vr1 = vr0 + (size_t)32 * (N_ / 8);
  const size_t krow = (size_t)b * N_ + 64 * w + li;

  for (int t = 0; t < 16; ++t) {
    const int kv0 = t << 8;
    const size_t kvo = (size_t)(kv0 >> 3);
    char* Pb = (char*)sm.P[t & 1];

    // ---- issue K loads for this iter, then V(ct=0) prefetch for phase 2 ----
    short8 kf[2][4];
#pragma unroll
    for (int nt = 0; nt < 2; ++nt)
#pragma unroll
      for (int ks = 0; ks < 4; ++ks)
        kf[nt][ks] = Kt8[(krow + kv0 + 32 * nt) * 8 + 2 * ks + hi];

    short8 vp[16];  // V rows 64w+li (ct=0), whole 256-kv block; in flight
#pragma unroll
    for (int ks = 0; ks < 16; ++ks) vp[ks] = V8[vr0 + kvo + 2 * ks + hi];

    // ---- phase 1: S for kv-slice [kv0+64w, +64), 64 m-rows ----
#pragma unroll
    for (int nt = 0; nt < 2; ++nt) {
#pragma unroll
      for (int mt = 0; mt < 2; ++mt) {
        f32x16 st;
#pragma unroll
        for (int r = 0; r < 16; ++r) st[r] = 0.f;
#pragma unroll
        for (int ks = 0; ks < 4; ++ks)
          st = __builtin_amdgcn_mfma_f32_32x32x16_bf16(kf[nt][ks], qb[mt][ks], st, 0, 0, 0);
        // S^T tile: lane holds m = m0+32*mt+li, n_local = (r&3)+8*(r>>2)+4*hi
        float e[16];
        float ds = 0.f;
#pragma unroll
        for (int r = 0; r < 16; ++r) {
          e[r] = EXP2F(st[r]);
          ds += e[r];
        }
        den[mt] += ds;
        // e[4u..4u+3] are n_local = 8u+4hi+{0..3}: one 8-byte LDS write each
        char* rp = Pb + (32 * mt + li) * 512;
#pragma unroll
        for (int u = 0; u < 4; ++u) {
          unsigned lo = cvtpk(e[4 * u], e[4 * u + 1]);
          unsigned hh = cvtpk(e[4 * u + 2], e[4 * u + 3]);
          unsigned long long vv = (unsigned long long)lo | ((unsigned long long)hh << 32);
          int colbyte = 128 * w + 64 * nt + 16 * u + 8 * hi;
          *(unsigned long long*)(rp + (colbyte ^ swz)) = vv;
        }
      }
    }
    __syncthreads();  // P[t&1] complete; dbuf protects write-after-read

    // ---- phase 2: PV for channel slice, all 256 kv of this block ----
    short8 v1[16];  // ct=1 ring, 4 deep
#pragma unroll
    for (int ks = 0; ks < 4; ++ks) v1[ks] = V8[vr1 + kvo + 2 * ks + hi];
#pragma unroll
    for (int ks = 0; ks < 16; ++ks) {
      if (ks + 4 < 16) v1[ks + 4] = V8[vr1 + kvo + 2 * (ks + 4) + hi];
      const int cb = (32 * ks + 16 * hi) ^ swz;
      const short8 pf0 = *(const short8*)(Pb + li * 512 + cb);
      const short8 pf1 = *(const short8*)(Pb + (32 + li) * 512 + cb);
      acc[0][0] = __builtin_amdgcn_mfma_f32_32x32x16_bf16(pf0, vp[ks], acc[0][0], 0, 0, 0);
      acc[1][0] = __builtin_amdgcn_mfma_f32_32x32x16_bf16(pf1, vp[ks], acc[1][0], 0, 0, 0);
      acc[0][1] = __builtin_amdgcn_mfma_f32_32x32x16_bf16(pf0, v1[ks], acc[0][1], 0, 0, 0);
      acc[1][1] = __builtin_amdgcn_mfma_f32_32x32x16_bf16(pf1, v1[ks], acc[1][1], 0, 0, 0);
    }
  }

  // ---- den reduction across waves ----
#pragma unroll
  for (int mt = 0; mt < 2; ++mt) {
    float dh = den[mt] + __shfl_xor(den[mt], 32);  // wave w's kv-slice, m-row
    if (hi == 0) den_lds[w][mt][li] = dh;
  }
  __syncthreads();  // also: all P reads done (TB aliases P)

  const float g = gamma[0];
  float idn[2][16];
#pragma unroll
  for (int mt = 0; mt < 2; ++mt) {
    float dtot = den_lds[0][mt][li] + den_lds[1][mt][li] +
                 den_lds[2][mt][li] + den_lds[3][mt][li];
    float ig = g / dtot;  // lane li: gamma/den for m-row m0+32mt+li
#pragma unroll
    for (int r = 0; r < 16; ++r)
      idn[mt][r] = __shfl(ig, (r & 3) + 8 * (r >> 2) + 4 * hi);
  }

  // ---- epilogue: transpose 32x32 per (mt,ct) via LDS, out = x + (g/den)*o ----
#pragma unroll
  for (int mt = 0; mt < 2; ++mt) {
#pragma unroll
    for (int ct = 0; ct < 2; ++ct) {
#pragma unroll
      for (int r = 0; r < 16; ++r) {
        int mrel = (r & 3) + 8 * (r >> 2) + 4 * hi;
        sm.TB[w][mrel * 33 + li] = acc[mt][ct][r] * idn[mt][r];
      }
      __builtin_amdgcn_s_waitcnt(0);  // lgkmcnt(0): LDS writes visible in-wave
#pragma unroll
      for (int p = 0; p < 4; ++p) {
        int cl = (lane >> 3) + 8 * p;   // c within tile 0..31
        int mc = (lane & 7) * 4;        // m chunk 0..28
        f32x4 o;
#pragma unroll
        for (int i = 0; i < 4; ++i) o[i] = sm.TB[w][(mc + i) * 33 + cl];
        size_t off = ((size_t)b * C_ + 64 * w + 32 * ct + cl) * N_ + m0 + 32 * mt + mc;
        f32x4 xv = *(const f32x4*)(x + off);
#pragma unroll
        for (int i = 0; i < 4; ++i) o[i] = xv[i] + o[i];
        *(f32x4*)(out + off) = o;
      }
      __builtin_amdgcn_s_waitcnt(0);  // drain reads before next tile overwrites
    }
  }
}

// ---------------------------------------------------------------------------
extern "C" void kernel_launch(void* const* d_in, const int* in_sizes, int n_in,
                              void* d_out, int out_size, void* d_ws, size_t ws_size,
                              hipStream_t stream) {
  const float* x = (const float*)d_in[0];
  const float* Wq = (const float*)d_in[1];
  const float* bq = (const float*)d_in[2];
  const float* Wk = (const float*)d_in[3];
  const float* bk = (const float*)d_in[4];
  const float* Wv = (const float*)d_in[5];
  const float* bv = (const float*)d_in[6];
  const float* gamma = (const float*)d_in[7];
  float* out = (float*)d_out;

  char* ws = (char*)d_ws;
  unsigned short* Wc = (unsigned short*)(ws);                    // 196608 B
  float* biasc = (float*)(ws + 196608);                          // 1536 B
  unsigned short* Qt = (unsigned short*)(ws + 198144);           // 4 MiB
  unsigned short* Kt = (unsigned short*)(ws + 198144 + 4194304); // 4 MiB
  unsigned short* Vv = (unsigned short*)(ws + 198144 + 8388608); // 16 MiB
  // total ws use: ~25.4 MB

  prep_kernel<<<384, 256, 0, stream>>>(Wq, bq, Wk, bk, Wv, bv, Wc, biasc);
  proj_kernel<<<dim3(64, 8), 256, 0, stream>>>(x, Wc, biasc, Qt, Kt, Vv);
  flash_kernel<<<512, 256, 0, stream>>>(Qt, Kt, Vv, x, gamma, out);
}

// Round 4
// 189.371 us; speedup vs baseline: 1.7510x; 1.1635x over previous
//
#include <hip/hip_runtime.h>

// Self-attention block (non-local): B=8, C=256, H=W=64 -> N=4096, dk=64.
// out = x + gamma * softmax((Wq x)^T (Wk x) / 8) applied to (Wv x).
// Pipeline: prep (weights->bf16, fold log2e/8 into Wq) -> proj (MFMA GEMM,
// in-LDS transpose of x) -> flash (shared-P attention, m-block 64, kv-block
// 256: each wave computes S for a 64-kv slice (32x32 MFMA), packs P bf16 into
// swizzled LDS (dbuf, 1 barrier/iter); PV uses 16x16x32 MFMA so each V-frag
// (loaded from L2 with a short register ring) feeds 4 m-tiles, and the D
// layout (4 consecutive m per lane) lets the epilogue store f32x4 directly --
// no LDS transpose.  Max-free softmax (logits O(1) by construction).

typedef __attribute__((ext_vector_type(8)))  short short8;
typedef __attribute__((ext_vector_type(4)))  short short4v;
typedef __attribute__((ext_vector_type(16))) float f32x16;
typedef __attribute__((ext_vector_type(4)))  float f32x4;

#define B_   8
#define C_   256
#define N_   4096
#define DK_  64
// log2(e) / sqrt(dk) = 1.4426950408889634 / 8
#define QSCL 0.18033688011112043f

#if defined(__has_builtin)
#if __has_builtin(__builtin_amdgcn_exp2f)
#define EXP2F(x) __builtin_amdgcn_exp2f(x)
#else
#define EXP2F(x) exp2f(x)
#endif
#else
#define EXP2F(x) exp2f(x)
#endif

// float -> bf16 bits, round-to-nearest-even (inputs are finite; no NaN path)
__device__ __forceinline__ unsigned short bfb(float f) {
  unsigned u = __builtin_bit_cast(unsigned, f);
  unsigned r = (u + 0x7fffu + ((u >> 16) & 1u)) >> 16;
  return (unsigned short)r;
}

// packed f32x2 -> bf16x2 (low = a, high = b), RNE
__device__ __forceinline__ unsigned cvtpk(float a, float b) {
  unsigned r;
  asm("v_cvt_pk_bf16_f32 %0, %1, %2" : "=v"(r) : "v"(a), "v"(b));
  return r;
}

// ---------------------------------------------------------------------------
// Kernel 1: weight prep.  W'[384][256] bf16 = [Wq*QSCL ; Wk ; Wv], bias'[384].
// ---------------------------------------------------------------------------
__global__ void prep_kernel(const float* __restrict__ Wq, const float* __restrict__ bq,
                            const float* __restrict__ Wk, const float* __restrict__ bk,
                            const float* __restrict__ Wv, const float* __restrict__ bv,
                            unsigned short* __restrict__ Wc, float* __restrict__ biasc) {
  int idx = blockIdx.x * 256 + threadIdx.x;
  if (idx < 384 * 256) {
    int ch = idx >> 8, c = idx & 255;
    float v;
    if (ch < 64)       v = Wq[ch * 256 + c] * QSCL;
    else if (ch < 128) v = Wk[(ch - 64) * 256 + c];
    else               v = Wv[(ch - 128) * 256 + c];
    Wc[idx] = bfb(v);
  }
  if (idx < 384) {
    float bb;
    if (idx < 64)       bb = bq[idx] * QSCL;
    else if (idx < 128) bb = bk[idx - 64];
    else                bb = bv[idx - 128];
    biasc[idx] = bb;
  }
}

// ---------------------------------------------------------------------------
// Kernel 2: projections.  Per (batch, 64-row n-block): stage x[256c][64n]
// transposed into LDS as bf16 (XOR-swizzled), then OUT[n][ch] = Xt * W'^T via
// 32x32x16 bf16 MFMA.  Outputs: Qt,Kt [B][N][64] (n-major), V [B][C][N].
// ---------------------------------------------------------------------------
__global__ __launch_bounds__(256, 2) void proj_kernel(
    const float* __restrict__ x, const unsigned short* __restrict__ Wc,
    const float* __restrict__ biasc, unsigned short* __restrict__ Qt,
    unsigned short* __restrict__ Kt, unsigned short* __restrict__ V) {
  __shared__ unsigned short XT[64 * 256];  // [n][c] bf16, swizzled, 32 KiB
  const int tid = threadIdx.x;
  const int b = blockIdx.y;
  const int n0 = blockIdx.x * 64;

  // stage: x[b][c][n0+0..63] fp32 -> XT[n][c] bf16 (transpose), swizzle:
  // ushort idx = n*256 + (((c>>3) ^ (n&15))<<3) + (c&7)
  {
    const f32x4* x4 = (const f32x4*)(x + ((size_t)b * C_) * N_ + n0);
    int c = tid >> 4;                  // 0..15 (+16 per pass)
    const int nl = (tid & 15) << 2;    // 0,4,...,60
#pragma unroll
    for (int p = 0; p < 16; ++p, c += 16) {
      f32x4 v = x4[(size_t)c * (N_ / 4) + (nl >> 2)];
#pragma unroll
      for (int i = 0; i < 4; ++i) {
        int n = nl + i;
        XT[n * 256 + ((((c >> 3) ^ (n & 15)) << 3) | (c & 7))] = bfb(v[i]);
      }
    }
  }
  __syncthreads();

  const int lane = tid & 63, li = lane & 31, hi = lane >> 5;
  const int w = tid >> 6;
  const int ch0 = 96 * w;  // this wave's 96 output channels (3 x 32)

  f32x16 acc[2][3];
#pragma unroll
  for (int mt = 0; mt < 2; ++mt)
#pragma unroll
    for (int j = 0; j < 3; ++j)
#pragma unroll
      for (int r = 0; r < 16; ++r) acc[mt][j][r] = 0.f;

  const short8* Wc8 = (const short8*)Wc;
#pragma unroll
  for (int ks = 0; ks < 16; ++ks) {
    // A-frags: lane holds Xt[n=32*mt+li][c=16*ks+8*hi .. +8]
    int chunk = 2 * ks + hi;
    short8 a0 = *(const short8*)&XT[(li) * 256 + ((chunk ^ (li & 15)) << 3)];
    short8 a1 = *(const short8*)&XT[(32 + li) * 256 + ((chunk ^ (li & 15)) << 3)];
#pragma unroll
    for (int j = 0; j < 3; ++j) {
      short8 bf = Wc8[(size_t)(ch0 + 32 * j + li) * 32 + chunk];
      acc[0][j] = __builtin_amdgcn_mfma_f32_32x32x16_bf16(a0, bf, acc[0][j], 0, 0, 0);
      acc[1][j] = __builtin_amdgcn_mfma_f32_32x32x16_bf16(a1, bf, acc[1][j], 0, 0, 0);
    }
  }

  // epilogue: D[row=n][col=ch], row = (r&3)+8*(r>>2)+4*hi + 32*mt, col = li
#pragma unroll
  for (int j = 0; j < 3; ++j) {
    const int chb = ch0 + 32 * j;  // wave-uniform 32-block, never straddles Q/K/V
    const int ch = chb + li;
    const float bias = biasc[ch];
#pragma unroll
    for (int mt = 0; mt < 2; ++mt) {
      if (chb < 64) {
#pragma unroll
        for (int r = 0; r < 16; ++r) {
          int n = n0 + 32 * mt + (r & 3) + 8 * (r >> 2) + 4 * hi;
          Qt[((size_t)(b * N_ + n) << 6) + ch] = bfb(acc[mt][j][r] + bias);
        }
      } else if (chb < 128) {
#pragma unroll
        for (int r = 0; r < 16; ++r) {
          int n = n0 + 32 * mt + (r & 3) + 8 * (r >> 2) + 4 * hi;
          Kt[((size_t)(b * N_ + n) << 6) + (ch - 64)] = bfb(acc[mt][j][r] + bias);
        }
      } else {
        const int cv = ch - 128;
#pragma unroll
        for (int q = 0; q < 4; ++q) {  // 4 consecutive n per 8B store
          short4v pk;
#pragma unroll
          for (int i = 0; i < 4; ++i) pk[i] = (short)bfb(acc[mt][j][4 * q + i] + bias);
          int n = n0 + 32 * mt + 8 * q + 4 * hi;
          *(short4v*)&V[(size_t)(b * C_ + cv) * N_ + n] = pk;
        }
      }
    }
  }
}

// ---------------------------------------------------------------------------
// Kernel 3: attention.  Grid 512 x 256 threads (4 waves).
// b = id & 7 (batch <-> XCD), m0 = (id >> 3) * 64.
// Per 256-kv block: wave w computes S for kv-slice [64w,64w+64) x 64 m via
// 32x32 MFMA, writes P bf16 to swizzled LDS (dbuf, 1 barrier/iter); PV uses
// 16x16x32 MFMA: P A-frags from LDS (reuse 4 over ct), V B-frags from L2 via
// a distance-2 register ring (reuse 4 over mt).  P byte addr:
//   m*512 + ((2n & ~15) ^ ((m&31)<<4)) + (2n & 15).
// ---------------------------------------------------------------------------
__global__ __launch_bounds__(256, 2) void flash_kernel(
    const unsigned short* __restrict__ Qt, const unsigned short* __restrict__ Kt,
    const unsigned short* __restrict__ V, const float* __restrict__ x,
    const float* __restrict__ gamma, float* __restrict__ out) {
  __shared__ unsigned short P[2][64 * 256];  // 2 x 32 KiB, swizzled
  __shared__ float den_lds[4][2][32];

  const int tid = threadIdx.x;
  const int lane = tid & 63, li = lane & 31, hi = lane >> 5;
  const int lg = lane >> 4, lc = lane & 15;   // 16-lane group / in-group id
  const int w = tid >> 6;
  const int id = blockIdx.x;
  const int b = id & 7;                // batch == XCD (round-robin dispatch)
  const int m0 = (id >> 3) << 6;       // 64-row m-block

  const short8* Qt8 = (const short8*)Qt;
  const short8* Kt8 = (const short8*)Kt;

  // Q B-frags (32x32 QK): lane holds Qt[m0+32*mt+li][16*ks+8*hi .. +8]
  short8 qb[2][4];
#pragma unroll
  for (int mt = 0; mt < 2; ++mt)
#pragma unroll
    for (int ks = 0; ks < 4; ++ks)
      qb[mt][ks] = Qt8[((size_t)b * N_ + m0 + 32 * mt + li) * 8 + 2 * ks + hi];

  f32x4 acc16[4][4];  // [t16 m-subtile][ct c-subtile]
#pragma unroll
  for (int t16 = 0; t16 < 4; ++t16)
#pragma unroll
    for (int ct = 0; ct < 4; ++ct)
#pragma unroll
      for (int r = 0; r < 4; ++r) acc16[t16][ct][r] = 0.f;
  float den[2] = {0.f, 0.f};

  const int swz = li << 4;             // P-write swizzle ((m&31)<<4), m=32mt+li
  const size_t krow = (size_t)b * N_ + 64 * w + li;
  // V base for 16x16 B-frags: row c = 64w+16ct+lc, kv bytes 16*lg + ...
  const unsigned short* Vbase = V + ((size_t)b * C_ + 64 * w + lc) * N_ + 8 * lg;
  // P-read per-lane constants: t16 tile -> row m=16*t16+lc
  int prow[4], psw[4];
#pragma unroll
  for (int t16 = 0; t16 < 4; ++t16) {
    int m = 16 * t16 + lc;
    prow[t16] = m * 512;
    psw[t16] = (m & 31) << 4;
  }

  for (int t = 0; t < 16; ++t) {
    const int kv0 = t << 8;
    char* Pb = (char*)P[t & 1];

    // ---- K loads for this iter's S tiles ----
    short8 kf[2][4];
#pragma unroll
    for (int nt = 0; nt < 2; ++nt)
#pragma unroll
      for (int ks = 0; ks < 4; ++ks)
        kf[nt][ks] = Kt8[(krow + kv0 + 32 * nt) * 8 + 2 * ks + hi];

    // ---- phase 1: S for kv-slice [kv0+64w, +64), 64 m-rows (32x32) ----
#pragma unroll
    for (int nt = 0; nt < 2; ++nt) {
#pragma unroll
      for (int mt = 0; mt < 2; ++mt) {
        f32x16 st;
#pragma unroll
        for (int r = 0; r < 16; ++r) st[r] = 0.f;
#pragma unroll
        for (int ks = 0; ks < 4; ++ks)
          st = __builtin_amdgcn_mfma_f32_32x32x16_bf16(kf[nt][ks], qb[mt][ks], st, 0, 0, 0);
        // S^T tile: lane holds m = m0+32*mt+li, n_local = (r&3)+8*(r>>2)+4*hi
        float e[16];
        float ds = 0.f;
#pragma unroll
        for (int r = 0; r < 16; ++r) {
          e[r] = EXP2F(st[r]);
          ds += e[r];
        }
        den[mt] += ds;
        // e[4u..4u+3] are n_local = 8u+4hi+{0..3}: one 8-byte LDS write each
        char* rp = Pb + (32 * mt + li) * 512;
#pragma unroll
        for (int u = 0; u < 4; ++u) {
          unsigned lo = cvtpk(e[4 * u], e[4 * u + 1]);
          unsigned hh = cvtpk(e[4 * u + 2], e[4 * u + 3]);
          unsigned long long vv = (unsigned long long)lo | ((unsigned long long)hh << 32);
          int colbyte = 128 * w + 64 * nt + 16 * u + 8 * hi;
          *(unsigned long long*)(rp + (colbyte ^ swz)) = vv;
        }
      }
    }

    // ---- V ring preload (ks=0,1): completed by the barrier's vmcnt drain ----
    short8 vf[8][4];
#pragma unroll
    for (int ks = 0; ks < 2; ++ks)
#pragma unroll
      for (int ct = 0; ct < 4; ++ct)
        vf[ks][ct] = *(const short8*)(Vbase + (size_t)(16 * ct) * N_ + kv0 + 32 * ks);

    __syncthreads();  // P[t&1] complete; dbuf protects write-after-read

    // ---- phase 2: PV (16x16x32), 8 k-steps of 32 kv ----
#pragma unroll
    for (int ks = 0; ks < 8; ++ks) {
      if (ks + 2 < 8) {
#pragma unroll
        for (int ct = 0; ct < 4; ++ct)
          vf[ks + 2][ct] = *(const short8*)(Vbase + (size_t)(16 * ct) * N_ + kv0 + 32 * (ks + 2));
      }
      short8 pf[4];
#pragma unroll
      for (int t16 = 0; t16 < 4; ++t16)
        pf[t16] = *(const short8*)(Pb + prow[t16] + ((64 * ks + 16 * lg) ^ psw[t16]));
      __builtin_amdgcn_s_setprio(1);
#pragma unroll
      for (int ct = 0; ct < 4; ++ct)
#pragma unroll
        for (int t16 = 0; t16 < 4; ++t16)
          acc16[t16][ct] = __builtin_amdgcn_mfma_f32_16x16x32_bf16(
              pf[t16], vf[ks][ct], acc16[t16][ct], 0, 0, 0);
      __builtin_amdgcn_s_setprio(0);
    }
  }

  // ---- den reduction across waves ----
#pragma unroll
  for (int mt = 0; mt < 2; ++mt) {
    float dh = den[mt] + __shfl_xor(den[mt], 32);  // wave w's kv-slice, m=32mt+li
    if (hi == 0) den_lds[w][mt][li] = dh;
  }
  __syncthreads();

  const float g = gamma[0];
  float ig0, ig1;
  {
    float d0 = den_lds[0][0][li] + den_lds[1][0][li] + den_lds[2][0][li] + den_lds[3][0][li];
    float d1 = den_lds[0][1][li] + den_lds[1][1][li] + den_lds[2][1][li] + den_lds[3][1][li];
    ig0 = g / d0;  // lane li: gamma/den for m-row m0+li
    ig1 = g / d1;  // m-row m0+32+li
  }

  // ---- epilogue: D row = 4*lg + r (consecutive m), col c = 16*ct + lc ----
#pragma unroll
  for (int t16 = 0; t16 < 4; ++t16) {
    f32x4 idn;
#pragma unroll
    for (int r = 0; r < 4; ++r)
      idn[r] = __shfl(t16 < 2 ? ig0 : ig1, 16 * (t16 & 1) + 4 * lg + r);
#pragma unroll
    for (int ct = 0; ct < 4; ++ct) {
      size_t off = ((size_t)b * C_ + 64 * w + 16 * ct + lc) * N_ + m0 + 16 * t16 + 4 * lg;
      f32x4 xv = *(const f32x4*)(x + off);
      f32x4 o;
#pragma unroll
      for (int r = 0; r < 4; ++r) o[r] = xv[r] + idn[r] * acc16[t16][ct][r];
      *(f32x4*)(out + off) = o;
    }
  }
}

// ---------------------------------------------------------------------------
extern "C" void kernel_launch(void* const* d_in, const int* in_sizes, int n_in,
                              void* d_out, int out_size, void* d_ws, size_t ws_size,
                              hipStream_t stream) {
  const float* x = (const float*)d_in[0];
  const float* Wq = (const float*)d_in[1];
  const float* bq = (const float*)d_in[2];
  const float* Wk = (const float*)d_in[3];
  const float* bk = (const float*)d_in[4];
  const float* Wv = (const float*)d_in[5];
  const float* bv = (const float*)d_in[6];
  const float* gamma = (const float*)d_in[7];
  float* out = (float*)d_out;

  char* ws = (char*)d_ws;
  unsigned short* Wc = (unsigned short*)(ws);                    // 196608 B
  float* biasc = (float*)(ws + 196608);                          // 1536 B
  unsigned short* Qt = (unsigned short*)(ws + 198144);           // 4 MiB
  unsigned short* Kt = (unsigned short*)(ws + 198144 + 4194304); // 4 MiB
  unsigned short* Vv = (unsigned short*)(ws + 198144 + 8388608); // 16 MiB
  // total ws use: ~25.4 MB

  prep_kernel<<<384, 256, 0, stream>>>(Wq, bq, Wk, bk, Wv, bv, Wc, biasc);
  proj_kernel<<<dim3(64, 8), 256, 0, stream>>>(x, Wc, biasc, Qt, Kt, Vv);
  flash_kernel<<<512, 256, 0, stream>>>(Qt, Kt, Vv, x, gamma, out);
}

// Round 6
// 146.374 us; speedup vs baseline: 2.2654x; 1.2937x over previous
//
#include <hip/hip_runtime.h>

// Self-attention block (non-local): B=8, C=256, H=W=64 -> N=4096, dk=64.
// out = x + gamma * softmax((Wq x)^T (Wk x) / 8) applied to (Wv x).
// Pipeline: prep (weights->bf16, fold log2e/8 into Wq) -> proj (MFMA GEMM,
// in-LDS transpose of x) -> flash (shared-P attention, m-block 64, kv-block
// 128).  R6: V is staged into LDS via global_load_lds DMA (un-sinkable,
// drained free by the barrier's vmcnt(0)) with both-sides XOR swizzle:
// linear LDS dest + inverse-swizzled per-lane global source + swizzled read.
// P is packed bf16 into swizzled LDS.  2 barriers/iter, single-buffered.
// Max-free softmax (logits O(1) by construction), direct f32x4 epilogue.

typedef __attribute__((ext_vector_type(8)))  short short8;
typedef __attribute__((ext_vector_type(4)))  short short4v;
typedef __attribute__((ext_vector_type(16))) float f32x16;
typedef __attribute__((ext_vector_type(4)))  float f32x4;

#define B_   8
#define C_   256
#define N_   4096
#define DK_  64
// log2(e) / sqrt(dk) = 1.4426950408889634 / 8
#define QSCL 0.18033688011112043f

#if defined(__has_builtin)
#if __has_builtin(__builtin_amdgcn_exp2f)
#define EXP2F(x) __builtin_amdgcn_exp2f(x)
#else
#define EXP2F(x) exp2f(x)
#endif
#else
#define EXP2F(x) exp2f(x)
#endif

// float -> bf16 bits, round-to-nearest-even (inputs are finite; no NaN path)
__device__ __forceinline__ unsigned short bfb(float f) {
  unsigned u = __builtin_bit_cast(unsigned, f);
  unsigned r = (u + 0x7fffu + ((u >> 16) & 1u)) >> 16;
  return (unsigned short)r;
}

// packed f32x2 -> bf16x2 (low = a, high = b), RNE
__device__ __forceinline__ unsigned cvtpk(float a, float b) {
  unsigned r;
  asm("v_cvt_pk_bf16_f32 %0, %1, %2" : "=v"(r) : "v"(a), "v"(b));
  return r;
}

// ---------------------------------------------------------------------------
// Kernel 1: weight prep.  W'[384][256] bf16 = [Wq*QSCL ; Wk ; Wv], bias'[384].
// ---------------------------------------------------------------------------
__global__ void prep_kernel(const float* __restrict__ Wq, const float* __restrict__ bq,
                            const float* __restrict__ Wk, const float* __restrict__ bk,
                            const float* __restrict__ Wv, const float* __restrict__ bv,
                            unsigned short* __restrict__ Wc, float* __restrict__ biasc) {
  int idx = blockIdx.x * 256 + threadIdx.x;
  if (idx < 384 * 256) {
    int ch = idx >> 8, c = idx & 255;
    float v;
    if (ch < 64)       v = Wq[ch * 256 + c] * QSCL;
    else if (ch < 128) v = Wk[(ch - 64) * 256 + c];
    else               v = Wv[(ch - 128) * 256 + c];
    Wc[idx] = bfb(v);
  }
  if (idx < 384) {
    float bb;
    if (idx < 64)       bb = bq[idx] * QSCL;
    else if (idx < 128) bb = bk[idx - 64];
    else                bb = bv[idx - 128];
    biasc[idx] = bb;
  }
}

// ---------------------------------------------------------------------------
// Kernel 2: projections.  Per (batch, 64-row n-block): stage x[256c][64n]
// transposed into LDS as bf16 (XOR-swizzled), then OUT[n][ch] = Xt * W'^T via
// 32x32x16 bf16 MFMA.  Outputs: Qt,Kt [B][N][64] (n-major), V [B][C][N].
// ---------------------------------------------------------------------------
__global__ __launch_bounds__(256, 2) void proj_kernel(
    const float* __restrict__ x, const unsigned short* __restrict__ Wc,
    const float* __restrict__ biasc, unsigned short* __restrict__ Qt,
    unsigned short* __restrict__ Kt, unsigned short* __restrict__ V) {
  __shared__ unsigned short XT[64 * 256];  // [n][c] bf16, swizzled, 32 KiB
  const int tid = threadIdx.x;
  const int b = blockIdx.y;
  const int n0 = blockIdx.x * 64;

  // stage: x[b][c][n0+0..63] fp32 -> XT[n][c] bf16 (transpose), swizzle:
  // ushort idx = n*256 + (((c>>3) ^ (n&15))<<3) + (c&7)
  {
    const f32x4* x4 = (const f32x4*)(x + ((size_t)b * C_) * N_ + n0);
    int c = tid >> 4;                  // 0..15 (+16 per pass)
    const int nl = (tid & 15) << 2;    // 0,4,...,60
#pragma unroll
    for (int p = 0; p < 16; ++p, c += 16) {
      f32x4 v = x4[(size_t)c * (N_ / 4) + (nl >> 2)];
#pragma unroll
      for (int i = 0; i < 4; ++i) {
        int n = nl + i;
        XT[n * 256 + ((((c >> 3) ^ (n & 15)) << 3) | (c & 7))] = bfb(v[i]);
      }
    }
  }
  __syncthreads();

  const int lane = tid & 63, li = lane & 31, hi = lane >> 5;
  const int w = tid >> 6;
  const int ch0 = 96 * w;  // this wave's 96 output channels (3 x 32)

  f32x16 acc[2][3];
#pragma unroll
  for (int mt = 0; mt < 2; ++mt)
#pragma unroll
    for (int j = 0; j < 3; ++j)
#pragma unroll
      for (int r = 0; r < 16; ++r) acc[mt][j][r] = 0.f;

  const short8* Wc8 = (const short8*)Wc;
#pragma unroll
  for (int ks = 0; ks < 16; ++ks) {
    // A-frags: lane holds Xt[n=32*mt+li][c=16*ks+8*hi .. +8]
    int chunk = 2 * ks + hi;
    short8 a0 = *(const short8*)&XT[(li) * 256 + ((chunk ^ (li & 15)) << 3)];
    short8 a1 = *(const short8*)&XT[(32 + li) * 256 + ((chunk ^ (li & 15)) << 3)];
#pragma unroll
    for (int j = 0; j < 3; ++j) {
      short8 bf = Wc8[(size_t)(ch0 + 32 * j + li) * 32 + chunk];
      acc[0][j] = __builtin_amdgcn_mfma_f32_32x32x16_bf16(a0, bf, acc[0][j], 0, 0, 0);
      acc[1][j] = __builtin_amdgcn_mfma_f32_32x32x16_bf16(a1, bf, acc[1][j], 0, 0, 0);
    }
  }

  // epilogue: D[row=n][col=ch], row = (r&3)+8*(r>>2)+4*hi + 32*mt, col = li
#pragma unroll
  for (int j = 0; j < 3; ++j) {
    const int chb = ch0 + 32 * j;  // wave-uniform 32-block, never straddles Q/K/V
    const int ch = chb + li;
    const float bias = biasc[ch];
#pragma unroll
    for (int mt = 0; mt < 2; ++mt) {
      if (chb < 64) {
#pragma unroll
        for (int r = 0; r < 16; ++r) {
          int n = n0 + 32 * mt + (r & 3) + 8 * (r >> 2) + 4 * hi;
          Qt[((size_t)(b * N_ + n) << 6) + ch] = bfb(acc[mt][j][r] + bias);
        }
      } else if (chb < 128) {
#pragma unroll
        for (int r = 0; r < 16; ++r) {
          int n = n0 + 32 * mt + (r & 3) + 8 * (r >> 2) + 4 * hi;
          Kt[((size_t)(b * N_ + n) << 6) + (ch - 64)] = bfb(acc[mt][j][r] + bias);
        }
      } else {
        const int cv = ch - 128;
#pragma unroll
        for (int q = 0; q < 4; ++q) {  // 4 consecutive n per 8B store
          short4v pk;
#pragma unroll
          for (int i = 0; i < 4; ++i) pk[i] = (short)bfb(acc[mt][j][4 * q + i] + bias);
          int n = n0 + 32 * mt + 8 * q + 4 * hi;
          *(short4v*)&V[(size_t)(b * C_ + cv) * N_ + n] = pk;
        }
      }
    }
  }
}

// ---------------------------------------------------------------------------
// Kernel 3: attention.  Grid 512 x 256 threads (4 waves).
// b = id & 7 (batch <-> XCD), m0 = (id >> 3) * 64.  kv-block 128.
// Region A: issue V-tile DMA (global_load_lds, linear dest, inverse-swizzled
// source), load K frags, compute S for this wave's 32-kv slice x 64 m (32x32
// MFMA), exp2 + pack P bf16 into swizzled LDS.  syncthreads (drains DMA+P).
// Region B: PV with 16x16x32 MFMA, P A-frags + V B-frags from swizzled LDS.
// syncthreads.  LDS byte addr of T[row][kvbyte]: row*256 + (kvbyte ^
// ((row&7)<<4)) for both P (row=m) and V (row=c).
// ---------------------------------------------------------------------------
__global__ __launch_bounds__(256, 2) void flash_kernel(
    const unsigned short* __restrict__ Qt, const unsigned short* __restrict__ Kt,
    const unsigned short* __restrict__ V, const float* __restrict__ x,
    const float* __restrict__ gamma, float* __restrict__ out) {
  __shared__ unsigned short Vt[256 * 128];          // 64 KiB, swizzled V tile
  __shared__ union {
    unsigned short P[64 * 128];                     // 16 KiB, swizzled P tile
    float den[4][2][32];
  } sp;

  const int tid = threadIdx.x;
  const int lane = tid & 63, li = lane & 31, hi = lane >> 5;
  const int lg = lane >> 4, lc = lane & 15;   // 16-lane group / in-group id
  const int w = tid >> 6;
  const int id = blockIdx.x;
  const int b = id & 7;                // batch == XCD (round-robin dispatch)
  const int m0 = (id >> 3) << 6;       // 64-row m-block

  const short8* Qt8 = (const short8*)Qt;
  const short8* Kt8 = (const short8*)Kt;

  // Q B-frags (32x32 QK): lane holds Qt[m0+32*mt+li][16*ks+8*hi .. +8]
  short8 qb[2][4];
#pragma unroll
  for (int mt = 0; mt < 2; ++mt)
#pragma unroll
    for (int ks = 0; ks < 4; ++ks)
      qb[mt][ks] = Qt8[((size_t)b * N_ + m0 + 32 * mt + li) * 8 + 2 * ks + hi];

  f32x4 acc16[4][4];  // [t16 m-subtile][ct c-subtile]
#pragma unroll
  for (int t16 = 0; t16 < 4; ++t16)
#pragma unroll
    for (int ct = 0; ct < 4; ++ct)
#pragma unroll
      for (int r = 0; r < 4; ++r) acc16[t16][ct][r] = 0.f;
  float den[2] = {0.f, 0.f};

  // K rows for this wave's 32-kv slice: kv = kv0 + 32*w + li
  const size_t krow = (size_t)b * N_ + 32 * w + li;
  // V staging source base (bytes): batch start
  const char* vsb = (const char*)V + (size_t)(b * C_) * (N_ * 2);
  // P/V read constants
  int prow[4], psw[4];
#pragma unroll
  for (int t16 = 0; t16 < 4; ++t16) {
    int m = 16 * t16 + lc;
    prow[t16] = m * 256;
    psw[t16] = (m & 7) << 4;
  }
  int vrow[4], vsw[4];
#pragma unroll
  for (int ct = 0; ct < 4; ++ct) {
    int c = 64 * w + 16 * ct + lc;
    vrow[ct] = c * 256;
    vsw[ct] = (c & 7) << 4;
  }

  for (int t = 0; t < 32; ++t) {
    const int kv0 = t << 7;

    // ---- region A: V-tile DMA (un-sinkable), K loads, S, P pack ----
    // DMA: issue i covers LDS rows c = 64w + 4i .. +3 (linear dest); the
    // global source is inverse-swizzled so that swizzled reads see V[c][kv].
#pragma unroll
    for (int i = 0; i < 16; ++i) {
      int c = 64 * w + 4 * i + (lane >> 4);
      const char* src = vsb + (size_t)c * (N_ * 2) + (size_t)(kv0 * 2) +
                        (((lane & 15) << 4) ^ ((c & 7) << 4));
      __builtin_amdgcn_global_load_lds(
          (const __attribute__((address_space(1))) unsigned int*)src,
          (__attribute__((address_space(3))) unsigned int*)((char*)Vt + 16384 * w + 1024 * i),
          16, 0, 0);
    }

    short8 kf[4];
#pragma unroll
    for (int ks = 0; ks < 4; ++ks)
      kf[ks] = Kt8[(krow + kv0) * 8 + 2 * ks + hi];

#pragma unroll
    for (int mt = 0; mt < 2; ++mt) {
      f32x16 st;
#pragma unroll
      for (int r = 0; r < 16; ++r) st[r] = 0.f;
#pragma unroll
      for (int ks = 0; ks < 4; ++ks)
        st = __builtin_amdgcn_mfma_f32_32x32x16_bf16(kf[ks], qb[mt][ks], st, 0, 0, 0);
      // S^T tile: lane holds m = 32*mt + li, n_local = (r&3)+8*(r>>2)+4*hi
      float e[16];
      float ds = 0.f;
#pragma unroll
      for (int r = 0; r < 16; ++r) {
        e[r] = EXP2F(st[r]);
        ds += e[r];
      }
      den[mt] += ds;
      // e[4u..4u+3]: kv_local = 32w + 8u + 4hi + {0..3} -> 8B write at
      // kvbyte = 64w + 16u + 8hi, row m = 32mt+li, swizzle ^((m&7)<<4)
      char* rp = (char*)sp.P + (32 * mt + li) * 256;
      const int key = (li & 7) << 4;
#pragma unroll
      for (int u = 0; u < 4; ++u) {
        unsigned lo = cvtpk(e[4 * u], e[4 * u + 1]);
        unsigned hh = cvtpk(e[4 * u + 2], e[4 * u + 3]);
        unsigned long long vv = (unsigned long long)lo | ((unsigned long long)hh << 32);
        *(unsigned long long*)(rp + ((64 * w + 16 * u + 8 * hi) ^ key)) = vv;
      }
    }

    __syncthreads();  // drains DMA (vmcnt) + P writes (lgkm): tile ready

    // ---- region B: PV (16x16x32), 4 k-steps of 32 kv ----
#pragma unroll
    for (int ks = 0; ks < 4; ++ks) {
      const int kb = 64 * ks + 16 * lg;
      short8 pf[4], vf[4];
#pragma unroll
      for (int t16 = 0; t16 < 4; ++t16)
        pf[t16] = *(const short8*)((char*)sp.P + prow[t16] + (kb ^ psw[t16]));
#pragma unroll
      for (int ct = 0; ct < 4; ++ct)
        vf[ct] = *(const short8*)((char*)Vt + vrow[ct] + (kb ^ vsw[ct]));
      __builtin_amdgcn_s_setprio(1);
#pragma unroll
      for (int ct = 0; ct < 4; ++ct)
#pragma unroll
        for (int t16 = 0; t16 < 4; ++t16)
          acc16[t16][ct] = __builtin_amdgcn_mfma_f32_16x16x32_bf16(
              pf[t16], vf[ct], acc16[t16][ct], 0, 0, 0);
      __builtin_amdgcn_s_setprio(0);
    }

    __syncthreads();  // all P/V reads done before next iter overwrites
  }

  // ---- den reduction across waves (sp.den aliases P; reads are done) ----
#pragma unroll
  for (int mt = 0; mt < 2; ++mt) {
    float dh = den[mt] + __shfl_xor(den[mt], 32);  // full m-row over wave's kv
    if (hi == 0) sp.den[w][mt][li] = dh;
  }
  __syncthreads();

  const float g = gamma[0];
  float ig0, ig1;
  {
    float d0 = sp.den[0][0][li] + sp.den[1][0][li] + sp.den[2][0][li] + sp.den[3][0][li];
    float d1 = sp.den[0][1][li] + sp.den[1][1][li] + sp.den[2][1][li] + sp.den[3][1][li];
    ig0 = g / d0;  // lane li: gamma/den for m-row m0+li
    ig1 = g / d1;  // m-row m0+32+li
  }

  // ---- epilogue: D row = 4*lg + r (consecutive m), col c = 16*ct + lc ----
#pragma unroll
  for (int t16 = 0; t16 < 4; ++t16) {
    f32x4 idn;
#pragma unroll
    for (int r = 0; r < 4; ++r)
      idn[r] = __shfl(t16 < 2 ? ig0 : ig1, 16 * (t16 & 1) + 4 * lg + r);
#pragma unroll
    for (int ct = 0; ct < 4; ++ct) {
      size_t off = ((size_t)b * C_ + 64 * w + 16 * ct + lc) * N_ + m0 + 16 * t16 + 4 * lg;
      f32x4 xv = *(const f32x4*)(x + off);
      f32x4 o;
#pragma unroll
      for (int r = 0; r < 4; ++r) o[r] = xv[r] + idn[r] * acc16[t16][ct][r];
      *(f32x4*)(out + off) = o;
    }
  }
}

// ---------------------------------------------------------------------------
extern "C" void kernel_launch(void* const* d_in, const int* in_sizes, int n_in,
                              void* d_out, int out_size, void* d_ws, size_t ws_size,
                              hipStream_t stream) {
  const float* x = (const float*)d_in[0];
  const float* Wq = (const float*)d_in[1];
  const float* bq = (const float*)d_in[2];
  const float* Wk = (const float*)d_in[3];
  const float* bk = (const float*)d_in[4];
  const float* Wv = (const float*)d_in[5];
  const float* bv = (const float*)d_in[6];
  const float* gamma = (const float*)d_in[7];
  float* out = (float*)d_out;

  char* ws = (char*)d_ws;
  unsigned short* Wc = (unsigned short*)(ws);                    // 196608 B
  float* biasc = (float*)(ws + 196608);                          // 1536 B
  unsigned short* Qt = (unsigned short*)(ws + 198144);           // 4 MiB
  unsigned short* Kt = (unsigned short*)(ws + 198144 + 4194304); // 4 MiB
  unsigned short* Vv = (unsigned short*)(ws + 198144 + 8388608); // 16 MiB
  // total ws use: ~25.4 MB

  prep_kernel<<<384, 256, 0, stream>>>(Wq, bq, Wk, bk, Wv, bv, Wc, biasc);
  proj_kernel<<<dim3(64, 8), 256, 0, stream>>>(x, Wc, biasc, Qt, Kt, Vv);
  flash_kernel<<<512, 256, 0, stream>>>(Qt, Kt, Vv, x, gamma, out);
}